// Round 14
// baseline (124.029 us; speedup 1.0000x reference)
//
#include <hip/hip_runtime.h>
#include <hip/hip_bf16.h>
#include <cmath>

using bf16 = __hip_bfloat16;
typedef __attribute__((ext_vector_type(8))) short short8;
typedef __attribute__((ext_vector_type(4))) float floatx4;

#define B_      32
#define HH      56
#define WW      56
#define HIDDEN  96
#define HEADS   3
#define HD      32
#define WS_     7
#define DISP    3
#define NWH     8
#define NWW     8
#define NW      64
#define WS2     49
#define NFRAG_QKV (3*6*3*64)                      /* 3456 lane-frags */
#define NFRAG_OUT (6*3*64)                        /* 1152 lane-frags */
#define NPEL      (2*64*64)                       /* 8192 table entries */

#if __has_builtin(__builtin_amdgcn_exp2f)
#define EXP2(x) __builtin_amdgcn_exp2f(x)
#else
#define EXP2(x) exp2f(x)
#endif

__device__ inline unsigned short bf16_bits(float f) {
  unsigned u = __float_as_uint(f);
  unsigned r = u + 0x7fffu + ((u >> 16) & 1u);
  return (unsigned short)(r >> 16);
}

// packed f32x2 -> bf16x2 (RNE), single instruction on gfx950 (T12, m214)
__device__ inline unsigned cvtpk(float lo, float hi) {
  unsigned r;
  asm("v_cvt_pk_bf16_f32 %0, %1, %2" : "=v"(r) : "v"(lo), "v"(hi));
  return r;
}

// granule-XOR swizzled pointer into a [64][32]-ushort plane (64 B rows).
// Applied on BOTH write and read sides -> bijective, 16B-align preserved.
__device__ inline unsigned short* swz(const unsigned short* plane, int row, int boff) {
  return (unsigned short*)((char*)plane + (row << 6) + (boff ^ ((row & 3) << 4)));
}

// ---------------- Kernel 0: weight pre-swizzle + pos/mask table -----------
__global__ __launch_bounds__(256) void prep_kernel(
    const float* __restrict__ w_qkv, const float* __restrict__ w_out,
    const float* __restrict__ pos_emb,
    bf16* __restrict__ wfq, bf16* __restrict__ wfo, float* __restrict__ pelT) {
  int f = blockIdx.x * 256 + threadIdx.x;
  if (f < NFRAG_QKV) {
    int lane = f & 63, t = f >> 6;
    int kb = t % 3, t2 = t / 3, c6 = t2 % 6, ci = t2 / 6;
    int col = ci * 96 + c6 * 16 + (lane & 15);
    int k0 = kb * 32 + (lane >> 4) * 8;
    bf16 vals[8];
#pragma unroll
    for (int j = 0; j < 8; j++) vals[j] = __float2bfloat16(w_qkv[(k0 + j) * 288 + col]);
    *(short8*)&wfq[(size_t)f * 8] = *(const short8*)vals;
  } else if (f < NFRAG_QKV + NFRAG_OUT) {
    int fo = f - NFRAG_QKV;
    int lane = fo & 63, t = fo >> 6;
    int kb = t % 3, c6 = t / 3;
    int col = c6 * 16 + (lane & 15);
    int k0 = kb * 32 + (lane >> 4) * 8;
    bf16 vals[8];
#pragma unroll
    for (int j = 0; j < 8; j++) vals[j] = __float2bfloat16(w_out[(k0 + j) * 96 + col]);
    *(short8*)&wfo[(size_t)fo * 8] = *(const short8*)vals;
  } else {
    int p = f - (NFRAG_QKV + NFRAG_OUT);
    if (p < NPEL) {
      int mk = p >> 12, i = (p >> 6) & 63, j = p & 63;   // i = q-token, j = k-token
      int iy = i / WS_, ix = i % WS_, jy = j / WS_, jx = j % WS_;
      int idx = (jy - iy + 6) * 13 + (jx - ix + 6);
      idx = idx < 0 ? 0 : (idx > 168 ? 168 : idx);
      bool live = (i < WS2) && (j < WS2) && !(mk && ((i >= 28) != (j >= 28)));
      // pre-scaled by log2(e) so the kernel can use exp2 directly
      pelT[p] = live ? pos_emb[idx] * 1.4426950408889634f : -1e30f;
    }
  }
}

// ---------------- Fused kernel: one block per (batch, window) -------------
// LDS: slabA 12288 + slabB 12288 + vT 13824 = 38400 B -> 4 blocks/CU.
// af (QKV A-fragments) is WAVE-UNIFORM, so it is loaded DIRECTLY from
// global x into registers (no LDS staging; L2 merges the 4-wave overlap).
// This deletes the x-staging phase and two of R13's three barriers.
// Slabs granule-XOR swizzled; K stored PERMUTED in slabB (pi(16jt+4q+r) =
// 32(jt&1)+4(jt>>1)+8q+r) so the swapped-QK^T output IS the PV A-frag
// layout: P stays in registers. Phase 3 is STAGE-MAJOR. Phase 4 is
// WAVE-OWNS-M (same-wave DS write->read, no barrier — R13-verified).
// ONE barrier total: QKV production -> attention consumption.
__global__ __launch_bounds__(256, 4) void fused_swin_kernel(
    const float* __restrict__ x,
    const bf16* __restrict__ wfq, const bf16* __restrict__ wfo,
    const float* __restrict__ b_qkv, const float* __restrict__ b_out,
    const float* __restrict__ pelT, float* __restrict__ out) {

  __shared__ unsigned short slabA[3][64][32];  // q -> attn out
  __shared__ unsigned short slabB[3][64][32];  // k (per head, permuted rows)
  __shared__ unsigned short vT[3][32][72];     // v transposed (per head, [d][tok])

  const int blk = blockIdx.x;
  const int nw = blk & 63, b = blk >> 6;
  const int wy = nw >> 3, wx = nw & 7;
  const int tid = threadIdx.x;
  const int lane = tid & 63, wv = tid >> 6;
  const int n_ = lane & 15, quad = lane >> 4;

  // early prefetch of this wave's first QKV weight tile
  const short8* wfQ = (const short8*)wfq;
  short8 wcur0 = wfQ[(size_t)((wv * 3 + 0) * 64 + lane)];
  short8 wcur1 = wfQ[(size_t)((wv * 3 + 1) * 64 + lane)];
  short8 wcur2 = wfQ[(size_t)((wv * 3 + 2) * 64 + lane)];

  // ---- phase 1: A-fragments straight from global x (wave-uniform) ----
  short8 af[4][3];
#pragma unroll
  for (int m = 0; m < 4; m++) {
    const int row = 16 * m + n_;
    if (row < WS2) {
      const int py = row / WS_, px = row % WS_;
      int h = wy * WS_ + py + DISP; if (h >= HH) h -= HH;
      int w = wx * WS_ + px + DISP; if (w >= WW) w -= WW;
      const float* xr = &x[(size_t)((b * HH + h) * WW + w) * HIDDEN + quad * 8];
#pragma unroll
      for (int kb = 0; kb < 3; kb++) {
        const float4 a0 = *(const float4*)&xr[kb * 32];
        const float4 a1 = *(const float4*)&xr[kb * 32 + 4];
        union { unsigned u[4]; short8 s8; } fu;
        fu.u[0] = cvtpk(a0.x, a0.y);
        fu.u[1] = cvtpk(a0.z, a0.w);
        fu.u[2] = cvtpk(a1.x, a1.y);
        fu.u[3] = cvtpk(a1.z, a1.w);
        af[m][kb] = fu.s8;
      }
    } else {
      const short8 z8 = (short8){0, 0, 0, 0, 0, 0, 0, 0};
#pragma unroll
      for (int kb = 0; kb < 3; kb++) af[m][kb] = z8;
    }
  }

  // ---- pos-emb(+log2e) + mask from table, k-index follows K permutation --
  const bool maskedw = (nw >= NW - NWW);
  float pelv[4][4];
  {
    const float4* pt4 = (const float4*)&pelT[(maskedw ? 4096 : 0) + (16 * wv + n_) * 64];
#pragma unroll
    for (int jt = 0; jt < 4; jt++) {
      const float4 p4 = pt4[8 * (jt & 1) + (jt >> 1) + 2 * quad];
      pelv[jt][0] = p4.x; pelv[jt][1] = p4.y;
      pelv[jt][2] = p4.z; pelv[jt][3] = p4.w;
    }
  }

  // ---- phase 2b: QKV projection, N-split, 1-deep weight pipeline ----
  {
    // permuted destination row offset for K stores
    const int rB = 32 * ((n_ >> 2) & 1) + 4 * (n_ >> 3) + (n_ & 3);
    int t = wv;
    while (t < 18) {
      const int tn = t + 4;
      short8 wn0 = wcur0, wn1 = wcur1, wn2 = wcur2;
      if (tn < 18) {
        wn0 = wfQ[(size_t)((tn * 3 + 0) * 64 + lane)];
        wn1 = wfQ[(size_t)((tn * 3 + 1) * 64 + lane)];
        wn2 = wfQ[(size_t)((tn * 3 + 2) * 64 + lane)];
      }
      const int ci = t / 6, c6 = t % 6, head = c6 >> 1;
      floatx4 acc[4];
      if (ci < 2) {   // q,k: swapped -> D[d][tok] -> [tok][d] vector stores
        const float4 bq = *(const float4*)&b_qkv[t * 16 + 4 * quad];
#pragma unroll
        for (int m = 0; m < 4; m++) acc[m] = (floatx4){bq.x, bq.y, bq.z, bq.w};
#pragma unroll
        for (int m = 0; m < 4; m++) {
          acc[m] = __builtin_amdgcn_mfma_f32_16x16x32_bf16(wcur0, af[m][0], acc[m], 0, 0, 0);
          acc[m] = __builtin_amdgcn_mfma_f32_16x16x32_bf16(wcur1, af[m][1], acc[m], 0, 0, 0);
          acc[m] = __builtin_amdgcn_mfma_f32_16x16x32_bf16(wcur2, af[m][2], acc[m], 0, 0, 0);
        }
        const int boff = ((c6 & 1) << 5) + quad * 8;
        if (ci == 0) {          // q: natural rows
#pragma unroll
          for (int m = 0; m < 4; m++) {
            uint2 st;
            st.x = cvtpk(acc[m][0], acc[m][1]);
            st.y = cvtpk(acc[m][2], acc[m][3]);
            *(uint2*)swz(&slabA[head][0][0], 16 * m + n_, boff) = st;
          }
        } else {                // k: permuted rows
#pragma unroll
          for (int m = 0; m < 4; m++) {
            uint2 st;
            st.x = cvtpk(acc[m][0], acc[m][1]);
            st.y = cvtpk(acc[m][2], acc[m][3]);
            *(uint2*)swz(&slabB[head][0][0], rB + 8 * m, boff) = st;
          }
        }
      } else {        // v: normal -> D[tok][d] -> [d][tok] vector stores
        const float bias = b_qkv[t * 16 + n_];
#pragma unroll
        for (int m = 0; m < 4; m++) acc[m] = (floatx4){bias, bias, bias, bias};
#pragma unroll
        for (int m = 0; m < 4; m++) {
          acc[m] = __builtin_amdgcn_mfma_f32_16x16x32_bf16(af[m][0], wcur0, acc[m], 0, 0, 0);
          acc[m] = __builtin_amdgcn_mfma_f32_16x16x32_bf16(af[m][1], wcur1, acc[m], 0, 0, 0);
          acc[m] = __builtin_amdgcn_mfma_f32_16x16x32_bf16(af[m][2], wcur2, acc[m], 0, 0, 0);
        }
        const int dc = ((c6 & 1) << 4) + n_;
#pragma unroll
        for (int m = 0; m < 4; m++) {
          uint2 st;
          st.x = cvtpk(acc[m][0], acc[m][1]);
          st.y = cvtpk(acc[m][2], acc[m][3]);
          *(uint2*)&vT[head][dc][16 * m + 4 * quad] = st;
        }
      }
      wcur0 = wn0; wcur1 = wn1; wcur2 = wn2;
      t = tn;
    }
  }
  __syncthreads();   // the ONE barrier: q/k/vT production -> consumption

  // ---- phase 3: attention, STAGE-MAJOR across heads ----
  const float scale2 = 0.147244446f;  // 96^-0.5 * log2(e)
  const floatx4 zero4 = (floatx4){0.f, 0.f, 0.f, 0.f};

  // stage 1: all aq reads (before ANY slabA write), then all 12 QK MFMAs
  short8 aq[3];
#pragma unroll
  for (int h = 0; h < HEADS; h++)
    aq[h] = *(const short8*)swz(&slabA[h][0][0], 16 * wv + n_, quad * 16);
  floatx4 sAcc[3][4];
  __builtin_amdgcn_s_setprio(1);
#pragma unroll
  for (int h = 0; h < HEADS; h++)
#pragma unroll
    for (int jt = 0; jt < 4; jt++) {
      const short8 bk = *(const short8*)swz(&slabB[h][0][0], 16 * jt + n_, quad * 16);
      sAcc[h][jt] = __builtin_amdgcn_mfma_f32_16x16x32_bf16(bk, aq[h], zero4, 0, 0, 0);
    }
  __builtin_amdgcn_s_setprio(0);

  // stage 2: per-head softmax + PV; results packed into registers
  uint2 ost[3][2];
#pragma unroll
  for (int h = 0; h < HEADS; h++) {
    float ei[4][4];
    float s = 0.f;
#pragma unroll
    for (int jt = 0; jt < 4; jt++)
#pragma unroll
      for (int r = 0; r < 4; r++) {
        const float e = EXP2(fmaf(sAcc[h][jt][r], scale2, pelv[jt][r]));
        ei[jt][r] = e;
        s += e;
      }
    s += __shfl_xor(s, 16);
    s += __shfl_xor(s, 32);
    const float invq = s > 0.f ? __builtin_amdgcn_rcpf(s) : 0.f;

    // lane-local PV A-frags thanks to the K permutation
    unsigned pk2[4][2];
#pragma unroll
    for (int jt = 0; jt < 4; jt++) {
      pk2[jt][0] = cvtpk(ei[jt][0], ei[jt][1]);
      pk2[jt][1] = cvtpk(ei[jt][2], ei[jt][3]);
    }
    short8 apf[2];
#pragma unroll
    for (int kc = 0; kc < 2; kc++) {
      union { unsigned u[4]; short8 s8; } fu;
      fu.u[0] = pk2[kc][0];
      fu.u[1] = pk2[kc][1];
      fu.u[2] = pk2[2 + kc][0];
      fu.u[3] = pk2[2 + kc][1];
      apf[kc] = fu.s8;
    }

    // PV swapped: D[d][q]; invq is lane-local for this lane's q-token
    floatx4 oAcc[2] = {zero4, zero4};
    __builtin_amdgcn_s_setprio(1);
#pragma unroll
    for (int nt = 0; nt < 2; nt++)
#pragma unroll
      for (int kc = 0; kc < 2; kc++) {
        const short8 bv = *(const short8*)&vT[h][16 * nt + n_][32 * kc + quad * 8];
        oAcc[nt] = __builtin_amdgcn_mfma_f32_16x16x32_bf16(bv, apf[kc], oAcc[nt], 0, 0, 0);
      }
    __builtin_amdgcn_s_setprio(0);
#pragma unroll
    for (int nt = 0; nt < 2; nt++) {
      ost[h][nt].x = cvtpk(oAcc[nt][0] * invq, oAcc[nt][1] * invq);
      ost[h][nt].y = cvtpk(oAcc[nt][2] * invq, oAcc[nt][3] * invq);
    }
  }

  // stage 3: slabA stores (wave-private rows; consumed ONLY by this wave)
#pragma unroll
  for (int h = 0; h < HEADS; h++)
#pragma unroll
    for (int nt = 0; nt < 2; nt++)
      *(uint2*)swz(&slabA[h][0][0], 16 * wv + n_, nt * 32 + quad * 8) = ost[h][nt];
  // NO barrier: phase 4 reads only this wave's rows (same-wave DS ordering)

  // ---- phase 4: output projection, WAVE-OWNS-M (m = wv), all 6 t-tiles --
  short8 af2[3];
#pragma unroll
  for (int kb = 0; kb < 3; kb++)
    af2[kb] = *(const short8*)swz(&slabA[kb][0][0], 16 * wv + n_, quad * 16);

  const int baserow = 16 * wv + 4 * quad;
  unsigned obase[4];
#pragma unroll
  for (int r = 0; r < 4; r++) {
    const int row = baserow + r;
    const int py = row / WS_, px = row % WS_;
    int hg = wy * WS_ + py + DISP; if (hg >= HH) hg -= HH;
    int wg = wx * WS_ + px + DISP; if (wg >= WW) wg -= WW;
    obase[r] = (unsigned)(((b * HH + hg) * WW + wg) * HIDDEN + n_);
  }

  const short8* wfO = (const short8*)wfo;
  {
    short8 oc0 = wfO[(size_t)((0 * 3 + 0) * 64 + lane)];
    short8 oc1 = wfO[(size_t)((0 * 3 + 1) * 64 + lane)];
    short8 oc2 = wfO[(size_t)((0 * 3 + 2) * 64 + lane)];
    for (int t = 0; t < 6; t++) {
      short8 on0 = oc0, on1 = oc1, on2 = oc2;
      if (t < 5) {
        on0 = wfO[(size_t)(((t + 1) * 3 + 0) * 64 + lane)];
        on1 = wfO[(size_t)(((t + 1) * 3 + 1) * 64 + lane)];
        on2 = wfO[(size_t)(((t + 1) * 3 + 2) * 64 + lane)];
      }
      const float bias = b_out[t * 16 + n_];
      floatx4 acc = (floatx4){bias, bias, bias, bias};
      acc = __builtin_amdgcn_mfma_f32_16x16x32_bf16(af2[0], oc0, acc, 0, 0, 0);
      acc = __builtin_amdgcn_mfma_f32_16x16x32_bf16(af2[1], oc1, acc, 0, 0, 0);
      acc = __builtin_amdgcn_mfma_f32_16x16x32_bf16(af2[2], oc2, acc, 0, 0, 0);
#pragma unroll
      for (int r = 0; r < 4; r++)
        if (baserow + r < WS2)
          out[(size_t)obase[r] + t * 16] = acc[r];
      oc0 = on0; oc1 = on1; oc2 = on2;
    }
  }
}

extern "C" void kernel_launch(void* const* d_in, const int* in_sizes, int n_in,
                              void* d_out, int out_size, void* d_ws, size_t ws_size,
                              hipStream_t stream) {
  const float* x     = (const float*)d_in[0];
  const float* w_qkv = (const float*)d_in[1];
  const float* b_qkv = (const float*)d_in[2];
  const float* pos   = (const float*)d_in[3];
  const float* w_out = (const float*)d_in[4];
  const float* b_out = (const float*)d_in[5];
  float* out = (float*)d_out;

  bf16* wfq = (bf16*)d_ws;                                  // 27648 bf16
  bf16* wfo = wfq + (size_t)NFRAG_QKV * 8;                  // 9216 bf16
  float* pelT = (float*)((char*)d_ws + (size_t)(NFRAG_QKV + NFRAG_OUT) * 8 * 2);

  prep_kernel<<<50, 256, 0, stream>>>(w_qkv, w_out, pos, wfq, wfo, pelT);
  fused_swin_kernel<<<B_ * NW, 256, 0, stream>>>(x, wfq, wfo, b_qkv, b_out, pelT, out);
}

// Round 15
// 115.156 us; speedup vs baseline: 1.0771x; 1.0771x over previous
//
#include <hip/hip_runtime.h>
#include <hip/hip_bf16.h>
#include <cmath>

using bf16 = __hip_bfloat16;
typedef __attribute__((ext_vector_type(8))) short short8;
typedef __attribute__((ext_vector_type(4))) float floatx4;

#define B_      32
#define HH      56
#define WW      56
#define HIDDEN  96
#define HEADS   3
#define HD      32
#define WS_     7
#define DISP    3
#define NWH     8
#define NWW     8
#define NW      64
#define WS2     49
#define NFRAG_QKV (3*6*3*64)                      /* 3456 lane-frags */
#define NFRAG_OUT (6*3*64)                        /* 1152 lane-frags */
#define NPEL      (2*64*64)                       /* 8192 table entries */

#if __has_builtin(__builtin_amdgcn_exp2f)
#define EXP2(x) __builtin_amdgcn_exp2f(x)
#else
#define EXP2(x) exp2f(x)
#endif

__device__ inline unsigned short bf16_bits(float f) {
  unsigned u = __float_as_uint(f);
  unsigned r = u + 0x7fffu + ((u >> 16) & 1u);
  return (unsigned short)(r >> 16);
}

// packed f32x2 -> bf16x2 (RNE), single instruction on gfx950 (T12, m214)
__device__ inline unsigned cvtpk(float lo, float hi) {
  unsigned r;
  asm("v_cvt_pk_bf16_f32 %0, %1, %2" : "=v"(r) : "v"(lo), "v"(hi));
  return r;
}

// granule-XOR swizzled pointer into a [64][32]-ushort plane (64 B rows).
// Applied on BOTH write and read sides -> bijective, 16B-align preserved.
__device__ inline unsigned short* swz(const unsigned short* plane, int row, int boff) {
  return (unsigned short*)((char*)plane + (row << 6) + (boff ^ ((row & 3) << 4)));
}

// ---------------- Kernel 0: weight pre-swizzle + pos/mask table -----------
__global__ __launch_bounds__(256) void prep_kernel(
    const float* __restrict__ w_qkv, const float* __restrict__ w_out,
    const float* __restrict__ pos_emb,
    bf16* __restrict__ wfq, bf16* __restrict__ wfo, float* __restrict__ pelT) {
  int f = blockIdx.x * 256 + threadIdx.x;
  if (f < NFRAG_QKV) {
    int lane = f & 63, t = f >> 6;
    int kb = t % 3, t2 = t / 3, c6 = t2 % 6, ci = t2 / 6;
    int col = ci * 96 + c6 * 16 + (lane & 15);
    int k0 = kb * 32 + (lane >> 4) * 8;
    bf16 vals[8];
#pragma unroll
    for (int j = 0; j < 8; j++) vals[j] = __float2bfloat16(w_qkv[(k0 + j) * 288 + col]);
    *(short8*)&wfq[(size_t)f * 8] = *(const short8*)vals;
  } else if (f < NFRAG_QKV + NFRAG_OUT) {
    int fo = f - NFRAG_QKV;
    int lane = fo & 63, t = fo >> 6;
    int kb = t % 3, c6 = t / 3;
    int col = c6 * 16 + (lane & 15);
    int k0 = kb * 32 + (lane >> 4) * 8;
    bf16 vals[8];
#pragma unroll
    for (int j = 0; j < 8; j++) vals[j] = __float2bfloat16(w_out[(k0 + j) * 96 + col]);
    *(short8*)&wfo[(size_t)fo * 8] = *(const short8*)vals;
  } else {
    int p = f - (NFRAG_QKV + NFRAG_OUT);
    if (p < NPEL) {
      int mk = p >> 12, i = (p >> 6) & 63, j = p & 63;   // i = q-token, j = k-token
      int iy = i / WS_, ix = i % WS_, jy = j / WS_, jx = j % WS_;
      int idx = (jy - iy + 6) * 13 + (jx - ix + 6);
      idx = idx < 0 ? 0 : (idx > 168 ? 168 : idx);
      bool live = (i < WS2) && (j < WS2) && !(mk && ((i >= 28) != (j >= 28)));
      // pre-scaled by log2(e) so the kernel can use exp2 directly
      pelT[p] = live ? pos_emb[idx] * 1.4426950408889634f : -1e30f;
    }
  }
}

// ---------------- Fused kernel: one block per (batch, window) -------------
// LDS: slabA 12288 + slabB 12288 + vT 13824 + tokoff 256 = 38656 B -> 4/CU.
// Slabs granule-XOR swizzled; K stored PERMUTED in slabB (pi(16jt+4q+r) =
// 32(jt&1)+4(jt>>1)+8q+r) so the swapped-QK^T output IS the PV A-frag
// layout: P stays in registers. Phase 3 is STAGE-MAJOR. Phase 4 is
// WAVE-OWNS-M (wave wv = m-tile wv, all 6 t-tiles): every phase-4 input
// (af2 rows, tokoff rows) is produced by the SAME wave -> the 4th barrier
// is deleted (same-wave DS write->read pattern, verified in R1/R2's es).
// Remaining barriers: 3 (phase boundaries 1->2a, 2a->2b, 2b->3).
// NOTE (R14 post-mortem): x MUST be LDS-staged — direct-from-global af
// loads regressed 33->45us (latency-bound scattered loads, 4x duplicated).
__global__ __launch_bounds__(256, 4) void fused_swin_kernel(
    const float* __restrict__ x,
    const bf16* __restrict__ wfq, const bf16* __restrict__ wfo,
    const float* __restrict__ b_qkv, const float* __restrict__ b_out,
    const float* __restrict__ pelT, float* __restrict__ out) {

  __shared__ unsigned short slabA[3][64][32];  // x (32-ch groups) -> q -> attn out
  __shared__ unsigned short slabB[3][64][32];  // k (per head, permuted rows)
  __shared__ unsigned short vT[3][32][72];     // v transposed (per head, [d][tok])
  __shared__ unsigned tokoff[64];              // per-row x/out token offset (f32 elems)

  const int blk = blockIdx.x;
  const int nw = blk & 63, b = blk >> 6;
  const int wy = nw >> 3, wx = nw & 7;
  const int tid = threadIdx.x;
  const int lane = tid & 63, wv = tid >> 6;
  const int n_ = lane & 15, quad = lane >> 4;

  // early prefetch of this wave's first QKV weight tile
  const short8* wfQ = (const short8*)wfq;
  short8 wcur0 = wfQ[(size_t)((wv * 3 + 0) * 64 + lane)];
  short8 wcur1 = wfQ[(size_t)((wv * 3 + 1) * 64 + lane)];
  short8 wcur2 = wfQ[(size_t)((wv * 3 + 2) * 64 + lane)];

  // ---- phase 1: shifted gather of x. 4 threads/row x 6 segs ----
  {
    const int rowp = tid >> 2, s0 = tid & 3;
    const bool haveRow = rowp < WS2;
    const float* xrow = x;
    if (haveRow) {
      const int py = rowp / WS_, px = rowp % WS_;
      int h = wy * WS_ + py + DISP; if (h >= HH) h -= HH;
      int w = wx * WS_ + px + DISP; if (w >= WW) w -= WW;
      const unsigned toff = (unsigned)(((b * HH + h) * WW + w) * HIDDEN);
      xrow = x + toff;
      if (s0 == 0) tokoff[rowp] = toff;   // reused by phase 4 scatter (own wave)
    }
#pragma unroll
    for (int p = 0; p < 6; p++) {
      const int seg = s0 + 4 * p;                 // 0..23
      const int kb = seg >> 3;
      uint2 pk = (uint2){0u, 0u};
      if (haveRow) {
        const float4 xv = *(const float4*)&xrow[seg * 4];
        pk.x = cvtpk(xv.x, xv.y);
        pk.y = cvtpk(xv.z, xv.w);
      }
      *(uint2*)swz(&slabA[kb][0][0], rowp, (seg & 7) * 8) = pk;
    }
  }

  // ---- pos-emb(+log2e) + mask from table, k-index follows K permutation --
  const bool maskedw = (nw >= NW - NWW);
  float pelv[4][4];
  {
    const float4* pt4 = (const float4*)&pelT[(maskedw ? 4096 : 0) + (16 * wv + n_) * 64];
#pragma unroll
    for (int jt = 0; jt < 4; jt++) {
      const float4 p4 = pt4[8 * (jt & 1) + (jt >> 1) + 2 * quad];
      pelv[jt][0] = p4.x; pelv[jt][1] = p4.y;
      pelv[jt][2] = p4.z; pelv[jt][3] = p4.w;
    }
  }
  __syncthreads();

  // ---- phase 2a: every wave reads A-frags for all 4 m-tiles ----
  short8 af[4][3];
#pragma unroll
  for (int m = 0; m < 4; m++)
#pragma unroll
    for (int kb = 0; kb < 3; kb++)
      af[m][kb] = *(const short8*)swz(&slabA[kb][0][0], 16 * m + n_, quad * 16);
  __syncthreads();  // slabA about to be overwritten by q

  // ---- phase 2b: QKV projection, N-split, 1-deep weight pipeline ----
  {
    // permuted destination row offset for K stores
    const int rB = 32 * ((n_ >> 2) & 1) + 4 * (n_ >> 3) + (n_ & 3);
    int t = wv;
    while (t < 18) {
      const int tn = t + 4;
      short8 wn0 = wcur0, wn1 = wcur1, wn2 = wcur2;
      if (tn < 18) {
        wn0 = wfQ[(size_t)((tn * 3 + 0) * 64 + lane)];
        wn1 = wfQ[(size_t)((tn * 3 + 1) * 64 + lane)];
        wn2 = wfQ[(size_t)((tn * 3 + 2) * 64 + lane)];
      }
      const int ci = t / 6, c6 = t % 6, head = c6 >> 1;
      floatx4 acc[4];
      if (ci < 2) {   // q,k: swapped -> D[d][tok] -> [tok][d] vector stores
        const float4 bq = *(const float4*)&b_qkv[t * 16 + 4 * quad];
#pragma unroll
        for (int m = 0; m < 4; m++) acc[m] = (floatx4){bq.x, bq.y, bq.z, bq.w};
#pragma unroll
        for (int m = 0; m < 4; m++) {
          acc[m] = __builtin_amdgcn_mfma_f32_16x16x32_bf16(wcur0, af[m][0], acc[m], 0, 0, 0);
          acc[m] = __builtin_amdgcn_mfma_f32_16x16x32_bf16(wcur1, af[m][1], acc[m], 0, 0, 0);
          acc[m] = __builtin_amdgcn_mfma_f32_16x16x32_bf16(wcur2, af[m][2], acc[m], 0, 0, 0);
        }
        const int boff = ((c6 & 1) << 5) + quad * 8;
        if (ci == 0) {          // q: natural rows
#pragma unroll
          for (int m = 0; m < 4; m++) {
            uint2 st;
            st.x = cvtpk(acc[m][0], acc[m][1]);
            st.y = cvtpk(acc[m][2], acc[m][3]);
            *(uint2*)swz(&slabA[head][0][0], 16 * m + n_, boff) = st;
          }
        } else {                // k: permuted rows
#pragma unroll
          for (int m = 0; m < 4; m++) {
            uint2 st;
            st.x = cvtpk(acc[m][0], acc[m][1]);
            st.y = cvtpk(acc[m][2], acc[m][3]);
            *(uint2*)swz(&slabB[head][0][0], rB + 8 * m, boff) = st;
          }
        }
      } else {        // v: normal -> D[tok][d] -> [d][tok] vector stores
        const float bias = b_qkv[t * 16 + n_];
#pragma unroll
        for (int m = 0; m < 4; m++) acc[m] = (floatx4){bias, bias, bias, bias};
#pragma unroll
        for (int m = 0; m < 4; m++) {
          acc[m] = __builtin_amdgcn_mfma_f32_16x16x32_bf16(af[m][0], wcur0, acc[m], 0, 0, 0);
          acc[m] = __builtin_amdgcn_mfma_f32_16x16x32_bf16(af[m][1], wcur1, acc[m], 0, 0, 0);
          acc[m] = __builtin_amdgcn_mfma_f32_16x16x32_bf16(af[m][2], wcur2, acc[m], 0, 0, 0);
        }
        const int dc = ((c6 & 1) << 4) + n_;
#pragma unroll
        for (int m = 0; m < 4; m++) {
          uint2 st;
          st.x = cvtpk(acc[m][0], acc[m][1]);
          st.y = cvtpk(acc[m][2], acc[m][3]);
          *(uint2*)&vT[head][dc][16 * m + 4 * quad] = st;
        }
      }
      wcur0 = wn0; wcur1 = wn1; wcur2 = wn2;
      t = tn;
    }
  }
  __syncthreads();

  // ---- phase 3: attention, STAGE-MAJOR across heads ----
  const float scale2 = 0.147244446f;  // 96^-0.5 * log2(e)
  const floatx4 zero4 = (floatx4){0.f, 0.f, 0.f, 0.f};

  // stage 1: all aq reads (before ANY slabA write), then all 12 QK MFMAs
  short8 aq[3];
#pragma unroll
  for (int h = 0; h < HEADS; h++)
    aq[h] = *(const short8*)swz(&slabA[h][0][0], 16 * wv + n_, quad * 16);
  floatx4 sAcc[3][4];
  __builtin_amdgcn_s_setprio(1);
#pragma unroll
  for (int h = 0; h < HEADS; h++)
#pragma unroll
    for (int jt = 0; jt < 4; jt++) {
      const short8 bk = *(const short8*)swz(&slabB[h][0][0], 16 * jt + n_, quad * 16);
      sAcc[h][jt] = __builtin_amdgcn_mfma_f32_16x16x32_bf16(bk, aq[h], zero4, 0, 0, 0);
    }
  __builtin_amdgcn_s_setprio(0);

  // stage 2: per-head softmax + PV; results packed into registers
  uint2 ost[3][2];
#pragma unroll
  for (int h = 0; h < HEADS; h++) {
    float ei[4][4];
    float s = 0.f;
#pragma unroll
    for (int jt = 0; jt < 4; jt++)
#pragma unroll
      for (int r = 0; r < 4; r++) {
        const float e = EXP2(fmaf(sAcc[h][jt][r], scale2, pelv[jt][r]));
        ei[jt][r] = e;
        s += e;
      }
    s += __shfl_xor(s, 16);
    s += __shfl_xor(s, 32);
    const float invq = s > 0.f ? __builtin_amdgcn_rcpf(s) : 0.f;

    // lane-local PV A-frags thanks to the K permutation
    unsigned pk2[4][2];
#pragma unroll
    for (int jt = 0; jt < 4; jt++) {
      pk2[jt][0] = cvtpk(ei[jt][0], ei[jt][1]);
      pk2[jt][1] = cvtpk(ei[jt][2], ei[jt][3]);
    }
    short8 apf[2];
#pragma unroll
    for (int kc = 0; kc < 2; kc++) {
      union { unsigned u[4]; short8 s8; } fu;
      fu.u[0] = pk2[kc][0];
      fu.u[1] = pk2[kc][1];
      fu.u[2] = pk2[2 + kc][0];
      fu.u[3] = pk2[2 + kc][1];
      apf[kc] = fu.s8;
    }

    // PV swapped: D[d][q]; invq is lane-local for this lane's q-token
    floatx4 oAcc[2] = {zero4, zero4};
    __builtin_amdgcn_s_setprio(1);
#pragma unroll
    for (int nt = 0; nt < 2; nt++)
#pragma unroll
      for (int kc = 0; kc < 2; kc++) {
        const short8 bv = *(const short8*)&vT[h][16 * nt + n_][32 * kc + quad * 8];
        oAcc[nt] = __builtin_amdgcn_mfma_f32_16x16x32_bf16(bv, apf[kc], oAcc[nt], 0, 0, 0);
      }
    __builtin_amdgcn_s_setprio(0);
#pragma unroll
    for (int nt = 0; nt < 2; nt++) {
      ost[h][nt].x = cvtpk(oAcc[nt][0] * invq, oAcc[nt][1] * invq);
      ost[h][nt].y = cvtpk(oAcc[nt][2] * invq, oAcc[nt][3] * invq);
    }
  }

  // stage 3: slabA stores (wave-private rows; consumed ONLY by this wave)
#pragma unroll
  for (int h = 0; h < HEADS; h++)
#pragma unroll
    for (int nt = 0; nt < 2; nt++)
      *(uint2*)swz(&slabA[h][0][0], 16 * wv + n_, nt * 32 + quad * 8) = ost[h][nt];
  // NO barrier: phase 4 reads only this wave's rows (same-wave DS ordering)

  // ---- phase 4: output projection, WAVE-OWNS-M (m = wv), all 6 t-tiles --
  short8 af2[3];
#pragma unroll
  for (int kb = 0; kb < 3; kb++)
    af2[kb] = *(const short8*)swz(&slabA[kb][0][0], 16 * wv + n_, quad * 16);

  const int baserow = 16 * wv + 4 * quad;
  unsigned obase[4];
#pragma unroll
  for (int r = 0; r < 4; r++)
    obase[r] = tokoff[baserow + r] + (unsigned)n_;

  const short8* wfO = (const short8*)wfo;
  {
    short8 oc0 = wfO[(size_t)((0 * 3 + 0) * 64 + lane)];
    short8 oc1 = wfO[(size_t)((0 * 3 + 1) * 64 + lane)];
    short8 oc2 = wfO[(size_t)((0 * 3 + 2) * 64 + lane)];
    for (int t = 0; t < 6; t++) {
      short8 on0 = oc0, on1 = oc1, on2 = oc2;
      if (t < 5) {
        on0 = wfO[(size_t)(((t + 1) * 3 + 0) * 64 + lane)];
        on1 = wfO[(size_t)(((t + 1) * 3 + 1) * 64 + lane)];
        on2 = wfO[(size_t)(((t + 1) * 3 + 2) * 64 + lane)];
      }
      const float bias = b_out[t * 16 + n_];
      floatx4 acc = (floatx4){bias, bias, bias, bias};
      acc = __builtin_amdgcn_mfma_f32_16x16x32_bf16(af2[0], oc0, acc, 0, 0, 0);
      acc = __builtin_amdgcn_mfma_f32_16x16x32_bf16(af2[1], oc1, acc, 0, 0, 0);
      acc = __builtin_amdgcn_mfma_f32_16x16x32_bf16(af2[2], oc2, acc, 0, 0, 0);
#pragma unroll
      for (int r = 0; r < 4; r++)
        if (baserow + r < WS2)
          out[(size_t)obase[r] + t * 16] = acc[r];
      oc0 = on0; oc1 = on1; oc2 = on2;
    }
  }
}

extern "C" void kernel_launch(void* const* d_in, const int* in_sizes, int n_in,
                              void* d_out, int out_size, void* d_ws, size_t ws_size,
                              hipStream_t stream) {
  const float* x     = (const float*)d_in[0];
  const float* w_qkv = (const float*)d_in[1];
  const float* b_qkv = (const float*)d_in[2];
  const float* pos   = (const float*)d_in[3];
  const float* w_out = (const float*)d_in[4];
  const float* b_out = (const float*)d_in[5];
  float* out = (float*)d_out;

  bf16* wfq = (bf16*)d_ws;                                  // 27648 bf16
  bf16* wfo = wfq + (size_t)NFRAG_QKV * 8;                  // 9216 bf16
  float* pelT = (float*)((char*)d_ws + (size_t)(NFRAG_QKV + NFRAG_OUT) * 8 * 2);

  prep_kernel<<<50, 256, 0, stream>>>(w_qkv, w_out, pos, wfq, wfo, pelT);
  fused_swin_kernel<<<B_ * NW, 256, 0, stream>>>(x, wfq, wfo, b_qkv, b_out, pelT, out);
}